// Round 17
// baseline (240.830 us; speedup 1.0000x reference)
//
#include <hip/hip_runtime.h>
#include <hip/hip_bf16.h>
#include <math.h>

#define D_MODEL 768
#define N_HEADS 12
#define D_HEAD  64
#define BATCH   2
#define SEQ     2048
#define ROWS    (BATCH*SEQ)          // 4096
#define D_FFN   (4*D_MODEL)          // 3072

typedef short bf16x8 __attribute__((ext_vector_type(8)));
typedef float f32x4  __attribute__((ext_vector_type(4)));

__device__ __forceinline__ short f2bf(float f) {
    __hip_bfloat16 h = __float2bfloat16(f);
    return *reinterpret_cast<short*>(&h);
}

// 16-lane DPP reductions; VALU-only, no LDS.
template<int CTRL>
__device__ __forceinline__ float dpp_f(float x) {
    int v = __builtin_amdgcn_update_dpp(0, __float_as_int(x), CTRL, 0xF, 0xF, true);
    return __int_as_float(v);
}
__device__ __forceinline__ float dpp_max16(float x) {
    x = fmaxf(x, dpp_f<0xB1>(x));    // quad_perm xor1
    x = fmaxf(x, dpp_f<0x4E>(x));    // quad_perm xor2
    x = fmaxf(x, dpp_f<0x141>(x));   // row_half_mirror
    x = fmaxf(x, dpp_f<0x140>(x));   // row_mirror
    return x;
}
__device__ __forceinline__ float dpp_sum16(float x) {
    x += dpp_f<0xB1>(x);
    x += dpp_f<0x4E>(x);
    x += dpp_f<0x141>(x);
    x += dpp_f<0x140>(x);
    return x;
}

// Score scale folding: scores = (Q K^T)*(qp kp^T)/64, softmax via exp2.
// sqrt(log2(e))/8 folded into BOTH Q and q_pos so sx*sp is already in
// log2-domain: p = exp2(sc - m). 0.15014031^2 = log2(e)/64.
#define QSCALE 0.15014031f

// ---------------------------------------------------------------- fused prep (+LN1)
// Segments: [0,576)Wq [576,1152)Wk [1152,1728)Wv [1728,2304)Wo
//           [2304,4608)W1 [4608,6912)W2 [6912,8448)qp [8448,9984)kp
//           [9984,14080) LN1 rows
__global__ __launch_bounds__(256)
void prep_kernel(const float* __restrict__ Wq, const float* __restrict__ Wk,
                 const float* __restrict__ Wv, const float* __restrict__ Wo,
                 const float* __restrict__ W1, const float* __restrict__ W2,
                 const float* __restrict__ q_pos, const float* __restrict__ k_pos,
                 const float* __restrict__ x, const float* __restrict__ ln1_g,
                 const float* __restrict__ ln1_b,
                 short* __restrict__ WTq, short* __restrict__ WTk,
                 short* __restrict__ WTv, short* __restrict__ WTo,
                 short* __restrict__ WT1, short* __restrict__ WT2,
                 short* __restrict__ qp_bf, short* __restrict__ kp_bf,
                 short* __restrict__ h_bf) {
    int id = blockIdx.x;
    if (id >= 9984) {   // LN1 segment
        int row = id - 9984;
        const float* xr = x + (size_t)row * D_MODEL;
        int t = threadIdx.x;
        float v0 = xr[t], v1 = xr[t + 256], v2 = xr[t + 512];
        float s  = v0 + v1 + v2;
        float s2 = v0*v0 + v1*v1 + v2*v2;
        __shared__ float rs[4], rs2[4];
        #pragma unroll
        for (int off = 32; off; off >>= 1) {
            s  += __shfl_down(s, off);
            s2 += __shfl_down(s2, off);
        }
        int wv = t >> 6, ln = t & 63;
        if (ln == 0) { rs[wv] = s; rs2[wv] = s2; }
        __syncthreads();
        float S  = rs[0] + rs[1] + rs[2] + rs[3];
        float S2 = rs2[0] + rs2[1] + rs2[2] + rs2[3];
        float mu  = S * (1.0f / D_MODEL);
        float var = S2 * (1.0f / D_MODEL) - mu * mu;
        float inv = rsqrtf(var + 1e-5f);
        short* orow = h_bf + (size_t)row * D_MODEL;
        orow[t]       = f2bf((v0 - mu) * inv * ln1_g[t]       + ln1_b[t]);
        orow[t + 256] = f2bf((v1 - mu) * inv * ln1_g[t + 256] + ln1_b[t + 256]);
        orow[t + 512] = f2bf((v2 - mu) * inv * ln1_g[t + 512] + ln1_b[t + 512]);
        return;
    }
    if (id >= 6912) {   // convert segment
        int cid = id - 6912;
        bool isq = (cid < 1536);
        int c = isq ? cid : cid - 1536;          // 1536 is NOT pow2: no & trick
        const float* src = isq ? q_pos : k_pos;
        short* dst = isq ? qp_bf : kp_bf;
        float sc = isq ? QSCALE : 1.0f;
        int i = (c * 256 + threadIdx.x) * 8;
        float4 a = *reinterpret_cast<const float4*>(src + i);
        float4 b = *reinterpret_cast<const float4*>(src + i + 4);
        bf16x8 r;
        r[0]=f2bf(a.x*sc); r[1]=f2bf(a.y*sc); r[2]=f2bf(a.z*sc); r[3]=f2bf(a.w*sc);
        r[4]=f2bf(b.x*sc); r[5]=f2bf(b.y*sc); r[6]=f2bf(b.z*sc); r[7]=f2bf(b.w*sc);
        *reinterpret_cast<bf16x8*>(dst + i) = r;
        return;
    }
    const float* W; short* WT; int K, N, t;
    if (id < 576)        { W = Wq; WT = WTq; K = 768;  N = 768;  t = id; }
    else if (id < 1152)  { W = Wk; WT = WTk; K = 768;  N = 768;  t = id - 576; }
    else if (id < 1728)  { W = Wv; WT = WTv; K = 768;  N = 768;  t = id - 1152; }
    else if (id < 2304)  { W = Wo; WT = WTo; K = 768;  N = 768;  t = id - 1728; }
    else if (id < 4608)  { W = W1; WT = WT1; K = 768;  N = 3072; t = id - 2304; }
    else                 { W = W2; WT = WT2; K = 3072; N = 768;  t = id - 4608; }
    int nb = N >> 5;
    int n0 = (t % nb) * 32, k0 = (t / nb) * 32;
    __shared__ float tile[32][33];
    int tx = threadIdx.x & 31, ty = threadIdx.x >> 5;   // 32 x 8
    #pragma unroll
    for (int i = 0; i < 4; ++i)
        tile[ty + 8*i][tx] = W[(size_t)(k0 + ty + 8*i) * N + n0 + tx];
    __syncthreads();
    #pragma unroll
    for (int i = 0; i < 4; ++i)
        WT[(size_t)(n0 + ty + 8*i) * K + k0 + tx] = f2bf(tile[tx][ty + 8*i]);
}

// Vm [ROWS][768] bf16 -> Vt [24][64][2048] bf16 (per-head V^T)
__global__ __launch_bounds__(256)
void transpose_v_kernel(const short* __restrict__ Vm, short* __restrict__ Vt) {
    __shared__ short tile[64][72];
    int kt = blockIdx.x;        // 32 k-tiles of 64
    int bh = blockIdx.y;        // 24
    int b = bh / N_HEADS, h = bh % N_HEADS;
    int tid = threadIdx.x;
    int row = tid >> 2, c16 = (tid & 3) * 16;
    const short* src = Vm + ((size_t)(b * SEQ) + kt * 64 + row) * D_MODEL + h * 64 + c16;
    *reinterpret_cast<bf16x8*>(&tile[row][c16])     = *reinterpret_cast<const bf16x8*>(src);
    *reinterpret_cast<bf16x8*>(&tile[row][c16 + 8]) = *reinterpret_cast<const bf16x8*>(src + 8);
    __syncthreads();
    int d = tid >> 2, k16 = (tid & 3) * 16;
    short o[16];
    #pragma unroll
    for (int j = 0; j < 16; ++j) o[j] = tile[k16 + j][d];
    short* dst = Vt + ((size_t)bh * 64 + d) * SEQ + kt * 64 + k16;
    *reinterpret_cast<bf16x8*>(dst)     = *reinterpret_cast<bf16x8*>(&o[0]);
    *reinterpret_cast<bf16x8*>(dst + 8) = *reinterpret_cast<bf16x8*>(&o[8]);
}

// ---------------------------------------------------------------- LN2 fused with Wo epilogue
// x2 = P0 + P1 + bo + x ; h_bf = LN(x2)
__global__ __launch_bounds__(256)
void ln2_fuse_kernel(const float* __restrict__ P0, const float* __restrict__ P1,
                     const float* __restrict__ bo, const float* __restrict__ x,
                     const float* __restrict__ g, const float* __restrict__ beta,
                     float* __restrict__ x2, short* __restrict__ out) {
    int row = blockIdx.x;
    size_t base = (size_t)row * D_MODEL;
    int t = threadIdx.x;
    float v0 = P0[base + t]       + P1[base + t]       + bo[t]       + x[base + t];
    float v1 = P0[base + t + 256] + P1[base + t + 256] + bo[t + 256] + x[base + t + 256];
    float v2 = P0[base + t + 512] + P1[base + t + 512] + bo[t + 512] + x[base + t + 512];
    x2[base + t] = v0; x2[base + t + 256] = v1; x2[base + t + 512] = v2;
    float s  = v0 + v1 + v2;
    float s2 = v0*v0 + v1*v1 + v2*v2;
    __shared__ float rs[4], rs2[4];
    #pragma unroll
    for (int off = 32; off; off >>= 1) {
        s  += __shfl_down(s, off);
        s2 += __shfl_down(s2, off);
    }
    int wv = t >> 6, ln = t & 63;
    if (ln == 0) { rs[wv] = s; rs2[wv] = s2; }
    __syncthreads();
    float S  = rs[0] + rs[1] + rs[2] + rs[3];
    float S2 = rs2[0] + rs2[1] + rs2[2] + rs2[3];
    float mu  = S * (1.0f / D_MODEL);
    float var = S2 * (1.0f / D_MODEL) - mu * mu;
    float inv = rsqrtf(var + 1e-5f);
    short* orow = out + base;
    orow[t]       = f2bf((v0 - mu) * inv * g[t]       + beta[t]);
    orow[t + 256] = f2bf((v1 - mu) * inv * g[t + 256] + beta[t + 256]);
    orow[t + 512] = f2bf((v2 - mu) * inv * g[t + 512] + beta[t + 512]);
}

// ---------------------------------------------------------------- bf16 MFMA GEMM
// Double-buffered LDS staging. ACT: 0 = bias[+res], 1 = bias+GELU, 2 = raw partial.
template<int ACT, bool RES, bool OUTBF>
__device__ __forceinline__
void gemm_body(const short* __restrict__ A, const short* __restrict__ WT,
               const float* __restrict__ bias, const float* __restrict__ res,
               void* __restrict__ Cout, int M, int N, int Kloop, int Kstride,
               float oscale) {
    __shared__ short As[2][128 * 32];
    __shared__ short Bs[2][128 * 32];
    const int tid = threadIdx.x;
    const int w = tid >> 6, lane = tid & 63;
    const int lr = lane & 15, lg = lane >> 4;
    const int wm = w >> 1, wn = w & 1;
    const int bm = blockIdx.y * 128, bn = blockIdx.x * 128;

    f32x4 acc[4][4] = {};

    const int srow = w * 32 + (lane >> 2);
    const int scol = (lane & 3) * 8;
    const short* Ag = A  + (size_t)(bm + srow) * Kstride + scol;
    const short* Bg = WT + (size_t)(bn + srow) * Kstride + scol;

    auto stage = [&](int k0, int buf) {
        #pragma unroll
        for (int r = 0; r < 2; ++r) {
            __builtin_amdgcn_global_load_lds(
                (const __attribute__((address_space(1))) void*)(Ag + (size_t)r * 16 * Kstride + k0),
                (__attribute__((address_space(3))) void*)(&As[buf][0] + w * 1024 + r * 512),
                16, 0, 0);
            __builtin_amdgcn_global_load_lds(
                (const __attribute__((address_space(1))) void*)(Bg + (size_t)r * 16 * Kstride + k0),
                (__attribute__((address_space(3))) void*)(&Bs[buf][0] + w * 1024 + r * 512),
                16, 0, 0);
        }
    };

    stage(0, 0);
    __syncthreads();
    int cur = 0;

    for (int k0 = 0; k0 < Kloop; k0 += 32) {
        if (k0 + 32 < Kloop) stage(k0 + 32, cur ^ 1);

        bf16x8 af[4], bfr[4];
        #pragma unroll
        for (int mi = 0; mi < 4; ++mi)
            af[mi] = *reinterpret_cast<const bf16x8*>(&As[cur][0] + (wm*64 + mi*16 + lr) * 32 + lg*8);
        #pragma unroll
        for (int nj = 0; nj < 4; ++nj)
            bfr[nj] = *reinterpret_cast<const bf16x8*>(&Bs[cur][0] + (wn*64 + nj*16 + lr) * 32 + lg*8);
        __builtin_amdgcn_s_setprio(1);
        #pragma unroll
        for (int mi = 0; mi < 4; ++mi)
            #pragma unroll
            for (int nj = 0; nj < 4; ++nj)
                acc[mi][nj] = __builtin_amdgcn_mfma_f32_16x16x32_bf16(af[mi], bfr[nj], acc[mi][nj], 0, 0, 0);
        __builtin_amdgcn_s_setprio(0);

        __syncthreads();
        cur ^= 1;
    }

    float bias_v[4] = {0.f, 0.f, 0.f, 0.f};
    if constexpr (ACT != 2) {
        #pragma unroll
        for (int nj = 0; nj < 4; ++nj) bias_v[nj] = bias[bn + wn*64 + nj*16 + lr];
    }

    #pragma unroll
    for (int mi = 0; mi < 4; ++mi) {
        #pragma unroll
        for (int j = 0; j < 4; ++j) {
            size_t m = bm + wm*64 + mi*16 + lg*4 + j;
            #pragma unroll
            for (int nj = 0; nj < 4; ++nj) {
                size_t n = bn + wn*64 + nj*16 + lr;
                float v = acc[mi][nj][j] + bias_v[nj];
                if (RES) v += res[m * N + n];
                if (ACT == 1) v = 0.5f * v * (1.0f + erff(v * 0.70710678118f));
                if (OUTBF) ((short*)Cout)[m * N + n] = f2bf(v * oscale);
                else       ((float*)Cout)[m * N + n] = v;
            }
        }
    }
}

template<int ACT, bool RES, bool OUTBF>
__global__ __launch_bounds__(256)
void gemm_mfma_kernel(const short* __restrict__ A, const short* __restrict__ WT,
                      const float* __restrict__ bias, const float* __restrict__ res,
                      void* __restrict__ Cout, int M, int N, int K) {
    gemm_body<ACT, RES, OUTBF>(A, WT, bias, res, Cout, M, N, K, K, 1.0f);
}

__global__ __launch_bounds__(256)
void gemm_qkv_kernel(const short* __restrict__ A,
                     const short* __restrict__ WTq, const short* __restrict__ WTk,
                     const short* __restrict__ WTv,
                     const float* __restrict__ bq, const float* __restrict__ bk,
                     const float* __restrict__ bv,
                     short* __restrict__ Qm, short* __restrict__ Km, short* __restrict__ Vm) {
    const short* WT; const float* bias; short* C; float sc;
    if (blockIdx.z == 0)      { WT = WTq; bias = bq; C = Qm; sc = QSCALE; }  // fold scale
    else if (blockIdx.z == 1) { WT = WTk; bias = bk; C = Km; sc = 1.0f; }
    else                      { WT = WTv; bias = bv; C = Vm; sc = 1.0f; }
    gemm_body<0, false, true>(A, WT, bias, nullptr, C, ROWS, D_MODEL, D_MODEL, D_MODEL, sc);
}

// Wo K-split: z in {0,1}, each half K=384, raw fp32 partials (384 blocks)
__global__ __launch_bounds__(256)
void gemm_wo_kernel(const short* __restrict__ ao, const short* __restrict__ WTo,
                    float* __restrict__ P0, float* __restrict__ P1) {
    int z = blockIdx.z;
    gemm_body<2, false, false>(ao + z * 384, WTo + z * 384, nullptr, nullptr,
                               z ? P1 : P0, ROWS, D_MODEL, 384, D_MODEL, 1.0f);
}

// W2 K-split: z in {0,1}, each half K=1536, raw fp32 partials (384 blocks)
__global__ __launch_bounds__(256)
void gemm_w2_kernel(const short* __restrict__ mid, const short* __restrict__ WT2,
                    float* __restrict__ P0, float* __restrict__ P1) {
    int z = blockIdx.z;
    gemm_body<2, false, false>(mid + z * 1536, WT2 + z * 1536, nullptr, nullptr,
                               z ? P1 : P0, ROWS, D_MODEL, 1536, D_FFN, 1.0f);
}

// out = P0 + P1 + b2 + x2
__global__ __launch_bounds__(256)
void w2_epi_kernel(const float* __restrict__ P0, const float* __restrict__ P1,
                   const float* __restrict__ b2, const float* __restrict__ x2,
                   float* __restrict__ out) {
    size_t i = ((size_t)blockIdx.x * 256 + threadIdx.x) * 4;
    int n = (int)(i % D_MODEL);
    float4 p0 = *reinterpret_cast<const float4*>(P0 + i);
    float4 p1 = *reinterpret_cast<const float4*>(P1 + i);
    float4 xr = *reinterpret_cast<const float4*>(x2 + i);
    float4 bb = *reinterpret_cast<const float4*>(b2 + n);
    float4 o;
    o.x = p0.x + p1.x + xr.x + bb.x;
    o.y = p0.y + p1.y + xr.y + bb.y;
    o.z = p0.z + p1.z + xr.z + bb.z;
    o.w = p0.w + p1.w + xr.w + bb.w;
    *reinterpret_cast<float4*>(out + i) = o;
}

// ---------------------------------------------------------------- MFMA flash attention v15
// = v14 but kp is NOT LDS-staged: kq B-frags load direct from global (L2-hit,
// dense 2KB/16-lane group). LDS 53760 -> 37376 B => 4 blocks/CU (8 waves).
// kq loads issued BEFORE stage(kt+1) so waiting on them (oldest vmcnt slots)
// doesn't drain the prefetch; sx cluster (LDS-only) runs in their shadow.
// Softmax in log2 domain (scale pre-folded): p = exp2(sc - m).
__global__ __launch_bounds__(128, 2)
void attn_mfma_kernel(const short* __restrict__ Q, const short* __restrict__ K,
                      const short* __restrict__ Vt, const short* __restrict__ qp,
                      const short* __restrict__ kp, short* __restrict__ ao) {
    __shared__ short Ks[2][4096];       // 64 keys x 64 d, swizzled
    __shared__ short Vts[2][4096];      // 64 d x 64 keys, swizzled
    __shared__ short Plds[2][16][72];   // per-wave P tile

    int lin = blockIdx.x;               // 0..767
    int wid = (lin & 7) * 96 + (lin >> 3);  // bijective XCD swizzle (768=8*96)
    int bh = wid >> 5;                  // 3 heads per XCD
    int pair = wid & 31;                // uniform-work pair index
    int b = bh / N_HEADS, h = bh % N_HEADS;
    int tid = threadIdx.x, w = tid >> 6, lane = tid & 63;
    int lr = lane & 15, lg = lane >> 4;

    const short* Kh  = K  + (size_t)(b * SEQ) * D_MODEL + h * 64;
    const short* kph = kp + (size_t)bh * SEQ * 64;
    const short* Vth = Vt + (size_t)bh * 64 * SEQ;

    const int s_sub  = lane >> 3;                      // row within 8-group
    const int s_colb = ((lane & 7) ^ s_sub) << 4;      // swizzled col byte

    auto stage = [&](int kt, int buf) {
        #pragma unroll
        for (int j = 0; j < 4; ++j) {
            int row = (w * 4 + j) * 8 + s_sub;
            int ldsoff = (w * 4 + j) * 1024;
            __builtin_amdgcn_global_load_lds(
                (const __attribute__((address_space(1))) void*)
                    ((const char*)(Kh + (size_t)(kt * 64 + row) * D_MODEL) + s_colb),
                (__attribute__((address_space(3))) void*)((char*)&Ks[buf][0] + ldsoff), 16, 0, 0);
            __builtin_amdgcn_global_load_lds(
                (const __attribute__((address_space(1))) void*)
                    ((const char*)(Vth + (size_t)row * SEQ + kt * 64) + s_colb),
                (__attribute__((address_space(3))) void*)((char*)&Vts[buf][0] + ldsoff), 16, 0, 0);
        }
    };
    auto ldr = [&](const short* base, int row, int halfb) -> bf16x8 {
        int off = row * 128 + ((halfb + lg * 16) ^ ((row & 7) << 4));
        return *reinterpret_cast<const bf16x8*>((const char*)base + off);
    };

    #pragma unroll
    for (int ph = 0; ph < 2; ++ph) {
        int qt = ph ? 63 - pair : pair;     // 32-row q-tile index, 0..63
        int qbase = qt * 32 + w * 16;

        const short* Qrow  = Q  + ((size_t)(b * SEQ) + qbase + lr) * D_MODEL + h * 64;
        const short* qprow = qp + ((size_t)bh * SEQ + qbase + lr) * 64;
        bf16x8 qf0  = *reinterpret_cast<const bf16x8*>(Qrow + lg * 8);
        bf16x8 qf1  = *reinterpret_cast<const bf16x8*>(Qrow + 32 + lg * 8);
        bf16x8 qpf0 = *reinterpret_cast<const bf16x8*>(qprow + lg * 8);
        bf16x8 qpf1 = *reinterpret_cast<const bf16x8*>(qprow + 32 + lg * 8);

        f32x4 o_acc[4] = {};
        float m_run[4], l_run[4];
        #pragma unroll
        for (int r = 0; r < 4; ++r) { m_run[r] = -1e30f; l_run[r] = 0.f; }

        int nkt = qt / 2 + 1;
        stage(0, 0);
        __syncthreads();                    // vmcnt(0) drained by compiler
        int cur = 0;

        for (int kt = 0; kt < nkt; ++kt) {
            // kq direct loads FIRST (oldest vmcnt slots)
            bf16x8 kq[4][2];
            #pragma unroll
            for (int sub = 0; sub < 4; ++sub) {
                const short* kpr = kph + (size_t)(kt * 64 + sub * 16 + lr) * 64;
                kq[sub][0] = *reinterpret_cast<const bf16x8*>(kpr + lg * 8);
                kq[sub][1] = *reinterpret_cast<const bf16x8*>(kpr + 32 + lg * 8);
            }
            if (kt + 1 < nkt) stage(kt + 1, cur ^ 1);

            const short* Kb = &Ks[cur][0];
            const short* Vb = &Vts[cur][0];
            f32x4 sx[4] = {}, sp[4] = {};
            __builtin_amdgcn_s_setprio(1);
            #pragma unroll
            for (int sub = 0; sub < 4; ++sub) {     // LDS-only: runs in kq shadow
                int row = sub * 16 + lr;
                bf16x8 kf0 = ldr(Kb, row, 0), kf1 = ldr(Kb, row, 64);
                sx[sub] = __builtin_amdgcn_mfma_f32_16x16x32_bf16(qf0, kf0, sx[sub], 0, 0, 0);
                sx[sub] = __builtin_amdgcn_mfma_f32_16x16x32_bf16(qf1, kf1, sx[sub], 0, 0, 0);
            }
            #pragma unroll
            for (int sub = 0; sub < 4; ++sub) {     // consumes kq
                sp[sub] = __builtin_amdgcn_mfma_f32_16x16x32_bf16(qpf0, kq[sub][0], sp[sub], 0, 0, 0);
                sp[sub] = __builtin_amdgcn_mfma_f32_16x16x32_bf16(qpf1, kq[sub][1], sp[sub], 0, 0, 0);
            }
            __builtin_amdgcn_s_setprio(0);

            // ---- combine + mask; per-row tile max (log2 domain)
            float sc[4][4];
            float pmax[4];
            bool diag = (kt == nkt - 1);
            #pragma unroll
            for (int r = 0; r < 4; ++r) {
                int row = qbase + lg * 4 + r;
                float mx = -1e30f;
                #pragma unroll
                for (int sub = 0; sub < 4; ++sub) {
                    float v = sx[sub][r] * sp[sub][r];
                    if (diag) {
                        int col = kt * 64 + sub * 16 + lr;
                        if (col > row) v = -1e30f;
                    }
                    sc[sub][r] = v;
                    mx = fmaxf(mx, v);
                }
                pmax[r] = dpp_max16(mx);
            }

            // ---- defer-max (T13): rescale only when some row exceeds m+8
            bool need = false;
            #pragma unroll
            for (int r = 0; r < 4; ++r) need = need || (pmax[r] > m_run[r] + 8.f);
            if (__any(need)) {
                #pragma unroll
                for (int r = 0; r < 4; ++r) {
                    float m_new = fmaxf(m_run[r], pmax[r]);
                    float scale = exp2f(m_run[r] - m_new);
                    m_run[r] = m_new;
                    l_run[r] *= scale;
                    #pragma unroll
                    for (int ds = 0; ds < 4; ++ds) o_acc[ds][r] *= scale;
                }
            }
            #pragma unroll
            for (int r = 0; r < 4; ++r) {
                float s = 0.f;
                #pragma unroll
                for (int sub = 0; sub < 4; ++sub) {
                    float pv = exp2f(sc[sub][r] - m_run[r]);
                    sc[sub][r] = pv;
                    s += pv;
                }
                l_run[r] += dpp_sum16(s);
            }

            // ---- P -> bf16 -> wave-private LDS -> A-frags
            #pragma unroll
            for (int sub = 0; sub < 4; ++sub)
                #pragma unroll
                for (int r = 0; r < 4; ++r)
                    Plds[w][lg * 4 + r][sub * 16 + lr] = f2bf(sc[sub][r]);

            bf16x8 pa0 = *reinterpret_cast<bf16x8*>(&Plds[w][lr][lg * 8]);
            bf16x8 pa1 = *reinterpret_cast<bf16x8*>(&Plds[w][lr][32 + lg * 8]);

            __builtin_amdgcn_s_setprio(1);
            #pragma unroll
            for (int ds = 0; ds < 4; ++ds) {
                int row = ds * 16 + lr;
                bf16x8 vb0 = ldr(Vb, row, 0), vb1 = ldr(Vb, row, 64);
                o_acc[ds] = __builtin_amdgcn_mfma_f32_16x16x32_bf16(pa0, vb0, o_acc[ds], 0, 0, 0);
                o_acc[ds] = __builtin_amdgcn_mfma_f32_16x16x32_bf16(pa1, vb1, o_acc[ds], 0, 0, 0);
            }
            __builtin_amdgcn_s_setprio(0);

            __syncthreads();
            cur ^= 1;
        }

        #pragma unroll
        for (int ds = 0; ds < 4; ++ds)
            #pragma unroll
            for (int r = 0; r < 4; ++r) {
                int row = qbase + lg * 4 + r;
                float val = o_acc[ds][r] / l_run[r];
                ao[((size_t)(b * SEQ) + row) * D_MODEL + h * 64 + ds * 16 + lr] = f2bf(val);
            }
        __syncthreads();   // phases share LDS buffers
    }
}

// ---------------------------------------------------------------- launch
extern "C" void kernel_launch(void* const* d_in, const int* in_sizes, int n_in,
                              void* d_out, int out_size, void* d_ws, size_t ws_size,
                              hipStream_t stream) {
    const float* x     = (const float*)d_in[0];
    const float* q_pos = (const float*)d_in[1];
    const float* k_pos = (const float*)d_in[2];
    const float* Wq = (const float*)d_in[4];
    const float* bq = (const float*)d_in[5];
    const float* Wk = (const float*)d_in[6];
    const float* bk = (const float*)d_in[7];
    const float* Wv = (const float*)d_in[8];
    const float* bv = (const float*)d_in[9];
    const float* Wo = (const float*)d_in[10];
    const float* bo = (const float*)d_in[11];
    const float* ln1_g = (const float*)d_in[12];
    const float* ln1_b = (const float*)d_in[13];
    const float* ln2_g = (const float*)d_in[14];
    const float* ln2_b = (const float*)d_in[15];
    const float* W1 = (const float*)d_in[16];
    const float* b1 = (const float*)d_in[17];
    const float* W2 = (const float*)d_in[18];
    const float* b2 = (const float*)d_in[19];
    float* out = (float*)d_out;

    char* p = (char*)d_ws;
    auto alloc = [&](size_t bytes) { char* q = p; p += (bytes + 255) & ~(size_t)255; return q; };
    const size_t SA = (size_t)ROWS * D_MODEL;
    const size_t SP = (size_t)BATCH * N_HEADS * SEQ * 64;

    short* h_bf  = (short*)alloc(SA * 2);
    short* Qm    = (short*)alloc(SA * 2);
    short* Km    = (short*)alloc(SA * 2);
    short* Vm    = (short*)alloc(SA * 2);
    short* Vt    = (short*)alloc(SP * 2);
    short* ao    = (short*)alloc(SA * 2);
    short* qp_bf = (short*)alloc(SP * 2);
    short* kp_bf = (short*)alloc(SP * 2);
    short* mid   = (short*)alloc((size_t)ROWS * D_FFN * 2);
    float* x2    = (float*)alloc(SA * 4);
    float* P0    = (float*)alloc(SA * 4);
    float* P1    = (float*)alloc(SA * 4);
    short* WTq   = (short*)alloc((size_t)D_MODEL * D_MODEL * 2);
    short* WTk   = (short*)alloc((size_t)D_MODEL * D_MODEL * 2);
    short* WTv   = (short*)alloc((size_t)D_MODEL * D_MODEL * 2);
    short* WTo   = (short*)alloc((size_t)D_MODEL * D_MODEL * 2);
    short* WT1   = (short*)alloc((size_t)D_MODEL * D_FFN * 2);
    short* WT2   = (short*)alloc((size_t)D_MODEL * D_FFN * 2);

    // fused prep: 6 transposes + 2 converts + LN1 in one dispatch
    prep_kernel<<<14080, 256, 0, stream>>>(Wq, Wk, Wv, Wo, W1, W2, q_pos, k_pos,
                                           x, ln1_g, ln1_b,
                                           WTq, WTk, WTv, WTo, WT1, WT2,
                                           qp_bf, kp_bf, h_bf);

    gemm_qkv_kernel<<<dim3(D_MODEL/128, ROWS/128, 3), 256, 0, stream>>>(
        h_bf, WTq, WTk, WTv, bq, bk, bv, Qm, Km, Vm);
    transpose_v_kernel<<<dim3(SEQ/64, BATCH*N_HEADS), 256, 0, stream>>>(Vm, Vt);
    attn_mfma_kernel<<<768, 128, 0, stream>>>(Qm, Km, Vt, qp_bf, kp_bf, ao);
    gemm_wo_kernel<<<dim3(D_MODEL/128, ROWS/128, 2), 256, 0, stream>>>(ao, WTo, P0, P1);
    ln2_fuse_kernel<<<ROWS, 256, 0, stream>>>(P0, P1, bo, x, ln2_g, ln2_b, x2, h_bf);
    gemm_mfma_kernel<1, false, true><<<dim3(D_FFN/128, ROWS/128), 256, 0, stream>>>(
        h_bf, WT1, b1, nullptr, mid, ROWS, D_FFN, D_MODEL);
    gemm_w2_kernel<<<dim3(D_MODEL/128, ROWS/128, 2), 256, 0, stream>>>(mid, WT2, P0, P1);
    w2_epi_kernel<<<(int)(SA/1024), 256, 0, stream>>>(P0, P1, b2, x2, out);
}

// Round 18
// 230.067 us; speedup vs baseline: 1.0468x; 1.0468x over previous
//
#include <hip/hip_runtime.h>
#include <hip/hip_bf16.h>
#include <math.h>

#define D_MODEL 768
#define N_HEADS 12
#define D_HEAD  64
#define BATCH   2
#define SEQ     2048
#define ROWS    (BATCH*SEQ)          // 4096
#define D_FFN   (4*D_MODEL)          // 3072

typedef short bf16x8 __attribute__((ext_vector_type(8)));
typedef float f32x4  __attribute__((ext_vector_type(4)));

__device__ __forceinline__ short f2bf(float f) {
    __hip_bfloat16 h = __float2bfloat16(f);
    return *reinterpret_cast<short*>(&h);
}

// 16-lane DPP reductions; VALU-only, no LDS.
template<int CTRL>
__device__ __forceinline__ float dpp_f(float x) {
    int v = __builtin_amdgcn_update_dpp(0, __float_as_int(x), CTRL, 0xF, 0xF, true);
    return __int_as_float(v);
}
__device__ __forceinline__ float dpp_max16(float x) {
    x = fmaxf(x, dpp_f<0xB1>(x));    // quad_perm xor1
    x = fmaxf(x, dpp_f<0x4E>(x));    // quad_perm xor2
    x = fmaxf(x, dpp_f<0x141>(x));   // row_half_mirror
    x = fmaxf(x, dpp_f<0x140>(x));   // row_mirror
    return x;
}
__device__ __forceinline__ float dpp_sum16(float x) {
    x += dpp_f<0xB1>(x);
    x += dpp_f<0x4E>(x);
    x += dpp_f<0x141>(x);
    x += dpp_f<0x140>(x);
    return x;
}

// Score scale folding: scores = (Q K^T)*(qp kp^T)/64, softmax via exp2.
// sqrt(log2(e))/8 folded into BOTH Q and q_pos so sx*sp is already in
// log2-domain: p = exp2(sc - m). 0.15014031^2 = log2(e)/64.
#define QSCALE 0.15014031f

// ---------------------------------------------------------------- fused prep (+LN1)
// Segments: [0,576)Wq [576,1152)Wk [1152,1728)Wv [1728,2304)Wo
//           [2304,4608)W1 [4608,6912)W2 [6912,8448)qp [8448,9984)kp
//           [9984,14080) LN1 rows
__global__ __launch_bounds__(256)
void prep_kernel(const float* __restrict__ Wq, const float* __restrict__ Wk,
                 const float* __restrict__ Wv, const float* __restrict__ Wo,
                 const float* __restrict__ W1, const float* __restrict__ W2,
                 const float* __restrict__ q_pos, const float* __restrict__ k_pos,
                 const float* __restrict__ x, const float* __restrict__ ln1_g,
                 const float* __restrict__ ln1_b,
                 short* __restrict__ WTq, short* __restrict__ WTk,
                 short* __restrict__ WTv, short* __restrict__ WTo,
                 short* __restrict__ WT1, short* __restrict__ WT2,
                 short* __restrict__ qp_bf, short* __restrict__ kp_bf,
                 short* __restrict__ h_bf) {
    int id = blockIdx.x;
    if (id >= 9984) {   // LN1 segment
        int row = id - 9984;
        const float* xr = x + (size_t)row * D_MODEL;
        int t = threadIdx.x;
        float v0 = xr[t], v1 = xr[t + 256], v2 = xr[t + 512];
        float s  = v0 + v1 + v2;
        float s2 = v0*v0 + v1*v1 + v2*v2;
        __shared__ float rs[4], rs2[4];
        #pragma unroll
        for (int off = 32; off; off >>= 1) {
            s  += __shfl_down(s, off);
            s2 += __shfl_down(s2, off);
        }
        int wv = t >> 6, ln = t & 63;
        if (ln == 0) { rs[wv] = s; rs2[wv] = s2; }
        __syncthreads();
        float S  = rs[0] + rs[1] + rs[2] + rs[3];
        float S2 = rs2[0] + rs2[1] + rs2[2] + rs2[3];
        float mu  = S * (1.0f / D_MODEL);
        float var = S2 * (1.0f / D_MODEL) - mu * mu;
        float inv = rsqrtf(var + 1e-5f);
        short* orow = h_bf + (size_t)row * D_MODEL;
        orow[t]       = f2bf((v0 - mu) * inv * ln1_g[t]       + ln1_b[t]);
        orow[t + 256] = f2bf((v1 - mu) * inv * ln1_g[t + 256] + ln1_b[t + 256]);
        orow[t + 512] = f2bf((v2 - mu) * inv * ln1_g[t + 512] + ln1_b[t + 512]);
        return;
    }
    if (id >= 6912) {   // convert segment
        int cid = id - 6912;
        bool isq = (cid < 1536);
        int c = isq ? cid : cid - 1536;          // 1536 is NOT pow2: no & trick
        const float* src = isq ? q_pos : k_pos;
        short* dst = isq ? qp_bf : kp_bf;
        float sc = isq ? QSCALE : 1.0f;
        int i = (c * 256 + threadIdx.x) * 8;
        float4 a = *reinterpret_cast<const float4*>(src + i);
        float4 b = *reinterpret_cast<const float4*>(src + i + 4);
        bf16x8 r;
        r[0]=f2bf(a.x*sc); r[1]=f2bf(a.y*sc); r[2]=f2bf(a.z*sc); r[3]=f2bf(a.w*sc);
        r[4]=f2bf(b.x*sc); r[5]=f2bf(b.y*sc); r[6]=f2bf(b.z*sc); r[7]=f2bf(b.w*sc);
        *reinterpret_cast<bf16x8*>(dst + i) = r;
        return;
    }
    const float* W; short* WT; int K, N, t;
    if (id < 576)        { W = Wq; WT = WTq; K = 768;  N = 768;  t = id; }
    else if (id < 1152)  { W = Wk; WT = WTk; K = 768;  N = 768;  t = id - 576; }
    else if (id < 1728)  { W = Wv; WT = WTv; K = 768;  N = 768;  t = id - 1152; }
    else if (id < 2304)  { W = Wo; WT = WTo; K = 768;  N = 768;  t = id - 1728; }
    else if (id < 4608)  { W = W1; WT = WT1; K = 768;  N = 3072; t = id - 2304; }
    else                 { W = W2; WT = WT2; K = 3072; N = 768;  t = id - 4608; }
    int nb = N >> 5;
    int n0 = (t % nb) * 32, k0 = (t / nb) * 32;
    __shared__ float tile[32][33];
    int tx = threadIdx.x & 31, ty = threadIdx.x >> 5;   // 32 x 8
    #pragma unroll
    for (int i = 0; i < 4; ++i)
        tile[ty + 8*i][tx] = W[(size_t)(k0 + ty + 8*i) * N + n0 + tx];
    __syncthreads();
    #pragma unroll
    for (int i = 0; i < 4; ++i)
        WT[(size_t)(n0 + ty + 8*i) * K + k0 + tx] = f2bf(tile[tx][ty + 8*i]);
}

// Vm [ROWS][768] bf16 -> Vt [24][64][2048] bf16 (per-head V^T)
__global__ __launch_bounds__(256)
void transpose_v_kernel(const short* __restrict__ Vm, short* __restrict__ Vt) {
    __shared__ short tile[64][72];
    int kt = blockIdx.x;        // 32 k-tiles of 64
    int bh = blockIdx.y;        // 24
    int b = bh / N_HEADS, h = bh % N_HEADS;
    int tid = threadIdx.x;
    int row = tid >> 2, c16 = (tid & 3) * 16;
    const short* src = Vm + ((size_t)(b * SEQ) + kt * 64 + row) * D_MODEL + h * 64 + c16;
    *reinterpret_cast<bf16x8*>(&tile[row][c16])     = *reinterpret_cast<const bf16x8*>(src);
    *reinterpret_cast<bf16x8*>(&tile[row][c16 + 8]) = *reinterpret_cast<const bf16x8*>(src + 8);
    __syncthreads();
    int d = tid >> 2, k16 = (tid & 3) * 16;
    short o[16];
    #pragma unroll
    for (int j = 0; j < 16; ++j) o[j] = tile[k16 + j][d];
    short* dst = Vt + ((size_t)bh * 64 + d) * SEQ + kt * 64 + k16;
    *reinterpret_cast<bf16x8*>(dst)     = *reinterpret_cast<bf16x8*>(&o[0]);
    *reinterpret_cast<bf16x8*>(dst + 8) = *reinterpret_cast<bf16x8*>(&o[8]);
}

// ---------------------------------------------------------------- LN2 fused with Wo epilogue
// x2 = P0 + P1 + bo + x ; h_bf = LN(x2)
__global__ __launch_bounds__(256)
void ln2_fuse_kernel(const float* __restrict__ P0, const float* __restrict__ P1,
                     const float* __restrict__ bo, const float* __restrict__ x,
                     const float* __restrict__ g, const float* __restrict__ beta,
                     float* __restrict__ x2, short* __restrict__ out) {
    int row = blockIdx.x;
    size_t base = (size_t)row * D_MODEL;
    int t = threadIdx.x;
    float v0 = P0[base + t]       + P1[base + t]       + bo[t]       + x[base + t];
    float v1 = P0[base + t + 256] + P1[base + t + 256] + bo[t + 256] + x[base + t + 256];
    float v2 = P0[base + t + 512] + P1[base + t + 512] + bo[t + 512] + x[base + t + 512];
    x2[base + t] = v0; x2[base + t + 256] = v1; x2[base + t + 512] = v2;
    float s  = v0 + v1 + v2;
    float s2 = v0*v0 + v1*v1 + v2*v2;
    __shared__ float rs[4], rs2[4];
    #pragma unroll
    for (int off = 32; off; off >>= 1) {
        s  += __shfl_down(s, off);
        s2 += __shfl_down(s2, off);
    }
    int wv = t >> 6, ln = t & 63;
    if (ln == 0) { rs[wv] = s; rs2[wv] = s2; }
    __syncthreads();
    float S  = rs[0] + rs[1] + rs[2] + rs[3];
    float S2 = rs2[0] + rs2[1] + rs2[2] + rs2[3];
    float mu  = S * (1.0f / D_MODEL);
    float var = S2 * (1.0f / D_MODEL) - mu * mu;
    float inv = rsqrtf(var + 1e-5f);
    short* orow = out + base;
    orow[t]       = f2bf((v0 - mu) * inv * g[t]       + beta[t]);
    orow[t + 256] = f2bf((v1 - mu) * inv * g[t + 256] + beta[t + 256]);
    orow[t + 512] = f2bf((v2 - mu) * inv * g[t + 512] + beta[t + 512]);
}

// ---------------------------------------------------------------- bf16 MFMA GEMM
// Double-buffered LDS staging. ACT: 0 = bias[+res], 1 = bias+GELU, 2 = raw partial.
template<int ACT, bool RES, bool OUTBF>
__device__ __forceinline__
void gemm_body(const short* __restrict__ A, const short* __restrict__ WT,
               const float* __restrict__ bias, const float* __restrict__ res,
               void* __restrict__ Cout, int M, int N, int Kloop, int Kstride,
               float oscale) {
    __shared__ short As[2][128 * 32];
    __shared__ short Bs[2][128 * 32];
    const int tid = threadIdx.x;
    const int w = tid >> 6, lane = tid & 63;
    const int lr = lane & 15, lg = lane >> 4;
    const int wm = w >> 1, wn = w & 1;
    const int bm = blockIdx.y * 128, bn = blockIdx.x * 128;

    f32x4 acc[4][4] = {};

    const int srow = w * 32 + (lane >> 2);
    const int scol = (lane & 3) * 8;
    const short* Ag = A  + (size_t)(bm + srow) * Kstride + scol;
    const short* Bg = WT + (size_t)(bn + srow) * Kstride + scol;

    auto stage = [&](int k0, int buf) {
        #pragma unroll
        for (int r = 0; r < 2; ++r) {
            __builtin_amdgcn_global_load_lds(
                (const __attribute__((address_space(1))) void*)(Ag + (size_t)r * 16 * Kstride + k0),
                (__attribute__((address_space(3))) void*)(&As[buf][0] + w * 1024 + r * 512),
                16, 0, 0);
            __builtin_amdgcn_global_load_lds(
                (const __attribute__((address_space(1))) void*)(Bg + (size_t)r * 16 * Kstride + k0),
                (__attribute__((address_space(3))) void*)(&Bs[buf][0] + w * 1024 + r * 512),
                16, 0, 0);
        }
    };

    stage(0, 0);
    __syncthreads();
    int cur = 0;

    for (int k0 = 0; k0 < Kloop; k0 += 32) {
        if (k0 + 32 < Kloop) stage(k0 + 32, cur ^ 1);

        bf16x8 af[4], bfr[4];
        #pragma unroll
        for (int mi = 0; mi < 4; ++mi)
            af[mi] = *reinterpret_cast<const bf16x8*>(&As[cur][0] + (wm*64 + mi*16 + lr) * 32 + lg*8);
        #pragma unroll
        for (int nj = 0; nj < 4; ++nj)
            bfr[nj] = *reinterpret_cast<const bf16x8*>(&Bs[cur][0] + (wn*64 + nj*16 + lr) * 32 + lg*8);
        __builtin_amdgcn_s_setprio(1);
        #pragma unroll
        for (int mi = 0; mi < 4; ++mi)
            #pragma unroll
            for (int nj = 0; nj < 4; ++nj)
                acc[mi][nj] = __builtin_amdgcn_mfma_f32_16x16x32_bf16(af[mi], bfr[nj], acc[mi][nj], 0, 0, 0);
        __builtin_amdgcn_s_setprio(0);

        __syncthreads();
        cur ^= 1;
    }

    float bias_v[4] = {0.f, 0.f, 0.f, 0.f};
    if constexpr (ACT != 2) {
        #pragma unroll
        for (int nj = 0; nj < 4; ++nj) bias_v[nj] = bias[bn + wn*64 + nj*16 + lr];
    }

    #pragma unroll
    for (int mi = 0; mi < 4; ++mi) {
        #pragma unroll
        for (int j = 0; j < 4; ++j) {
            size_t m = bm + wm*64 + mi*16 + lg*4 + j;
            #pragma unroll
            for (int nj = 0; nj < 4; ++nj) {
                size_t n = bn + wn*64 + nj*16 + lr;
                float v = acc[mi][nj][j] + bias_v[nj];
                if (RES) v += res[m * N + n];
                if (ACT == 1) v = 0.5f * v * (1.0f + erff(v * 0.70710678118f));
                if (OUTBF) ((short*)Cout)[m * N + n] = f2bf(v * oscale);
                else       ((float*)Cout)[m * N + n] = v;
            }
        }
    }
}

template<int ACT, bool RES, bool OUTBF>
__global__ __launch_bounds__(256)
void gemm_mfma_kernel(const short* __restrict__ A, const short* __restrict__ WT,
                      const float* __restrict__ bias, const float* __restrict__ res,
                      void* __restrict__ Cout, int M, int N, int K) {
    gemm_body<ACT, RES, OUTBF>(A, WT, bias, res, Cout, M, N, K, K, 1.0f);
}

__global__ __launch_bounds__(256)
void gemm_qkv_kernel(const short* __restrict__ A,
                     const short* __restrict__ WTq, const short* __restrict__ WTk,
                     const short* __restrict__ WTv,
                     const float* __restrict__ bq, const float* __restrict__ bk,
                     const float* __restrict__ bv,
                     short* __restrict__ Qm, short* __restrict__ Km, short* __restrict__ Vm) {
    const short* WT; const float* bias; short* C; float sc;
    if (blockIdx.z == 0)      { WT = WTq; bias = bq; C = Qm; sc = QSCALE; }  // fold scale
    else if (blockIdx.z == 1) { WT = WTk; bias = bk; C = Km; sc = 1.0f; }
    else                      { WT = WTv; bias = bv; C = Vm; sc = 1.0f; }
    gemm_body<0, false, true>(A, WT, bias, nullptr, C, ROWS, D_MODEL, D_MODEL, D_MODEL, sc);
}

// Wo K-split: z in {0,1}, each half K=384, raw fp32 partials (384 blocks)
__global__ __launch_bounds__(256)
void gemm_wo_kernel(const short* __restrict__ ao, const short* __restrict__ WTo,
                    float* __restrict__ P0, float* __restrict__ P1) {
    int z = blockIdx.z;
    gemm_body<2, false, false>(ao + z * 384, WTo + z * 384, nullptr, nullptr,
                               z ? P1 : P0, ROWS, D_MODEL, 384, D_MODEL, 1.0f);
}

// W2 K-split: z in {0,1}, each half K=1536, raw fp32 partials (384 blocks)
__global__ __launch_bounds__(256)
void gemm_w2_kernel(const short* __restrict__ mid, const short* __restrict__ WT2,
                    float* __restrict__ P0, float* __restrict__ P1) {
    int z = blockIdx.z;
    gemm_body<2, false, false>(mid + z * 1536, WT2 + z * 1536, nullptr, nullptr,
                               z ? P1 : P0, ROWS, D_MODEL, 1536, D_FFN, 1.0f);
}

// out = P0 + P1 + b2 + x2
__global__ __launch_bounds__(256)
void w2_epi_kernel(const float* __restrict__ P0, const float* __restrict__ P1,
                   const float* __restrict__ b2, const float* __restrict__ x2,
                   float* __restrict__ out) {
    size_t i = ((size_t)blockIdx.x * 256 + threadIdx.x) * 4;
    int n = (int)(i % D_MODEL);
    float4 p0 = *reinterpret_cast<const float4*>(P0 + i);
    float4 p1 = *reinterpret_cast<const float4*>(P1 + i);
    float4 xr = *reinterpret_cast<const float4*>(x2 + i);
    float4 bb = *reinterpret_cast<const float4*>(b2 + n);
    float4 o;
    o.x = p0.x + p1.x + xr.x + bb.x;
    o.y = p0.y + p1.y + xr.y + bb.y;
    o.z = p0.z + p1.z + xr.z + bb.z;
    o.w = p0.w + p1.w + xr.w + bb.w;
    *reinterpret_cast<float4*>(out + i) = o;
}

// ---------------------------------------------------------------- MFMA flash attention v16
// = r16's verified structure (all operands LDS-staged, double-buffered,
// 53760 B -> 3 blocks/CU) + exp2-domain softmax (scale pre-folded in Q/qp).
__global__ __launch_bounds__(128)
void attn_mfma_kernel(const short* __restrict__ Q, const short* __restrict__ K,
                      const short* __restrict__ Vt, const short* __restrict__ qp,
                      const short* __restrict__ kp, short* __restrict__ ao) {
    __shared__ short Ks[2][4096];       // 64 keys x 64 d, swizzled
    __shared__ short kps[2][4096];
    __shared__ short Vts[2][4096];      // 64 d x 64 keys, swizzled
    __shared__ short Plds[2][16][72];   // per-wave P tile (53760 B total)

    int lin = blockIdx.x;               // 0..767
    int wid = (lin & 7) * 96 + (lin >> 3);  // bijective XCD swizzle (768=8*96)
    int bh = wid >> 5;                  // 3 heads per XCD
    int pair = wid & 31;                // uniform-work pair index
    int b = bh / N_HEADS, h = bh % N_HEADS;
    int tid = threadIdx.x, w = tid >> 6, lane = tid & 63;
    int lr = lane & 15, lg = lane >> 4;

    const short* Kh  = K  + (size_t)(b * SEQ) * D_MODEL + h * 64;
    const short* kph = kp + (size_t)bh * SEQ * 64;
    const short* Vth = Vt + (size_t)bh * 64 * SEQ;

    const int s_sub  = lane >> 3;                      // row within 8-group
    const int s_colb = ((lane & 7) ^ s_sub) << 4;      // swizzled col byte

    auto stage = [&](int kt, int buf) {
        #pragma unroll
        for (int j = 0; j < 4; ++j) {
            int row = (w * 4 + j) * 8 + s_sub;
            int ldsoff = (w * 4 + j) * 1024;
            __builtin_amdgcn_global_load_lds(
                (const __attribute__((address_space(1))) void*)
                    ((const char*)(Kh + (size_t)(kt * 64 + row) * D_MODEL) + s_colb),
                (__attribute__((address_space(3))) void*)((char*)&Ks[buf][0] + ldsoff), 16, 0, 0);
            __builtin_amdgcn_global_load_lds(
                (const __attribute__((address_space(1))) void*)
                    ((const char*)(kph + (size_t)(kt * 64 + row) * 64) + s_colb),
                (__attribute__((address_space(3))) void*)((char*)&kps[buf][0] + ldsoff), 16, 0, 0);
            __builtin_amdgcn_global_load_lds(
                (const __attribute__((address_space(1))) void*)
                    ((const char*)(Vth + (size_t)row * SEQ + kt * 64) + s_colb),
                (__attribute__((address_space(3))) void*)((char*)&Vts[buf][0] + ldsoff), 16, 0, 0);
        }
    };
    auto ldr = [&](const short* base, int row, int halfb) -> bf16x8 {
        int off = row * 128 + ((halfb + lg * 16) ^ ((row & 7) << 4));
        return *reinterpret_cast<const bf16x8*>((const char*)base + off);
    };

    #pragma unroll
    for (int ph = 0; ph < 2; ++ph) {
        int qt = ph ? 63 - pair : pair;     // 32-row q-tile index, 0..63
        int qbase = qt * 32 + w * 16;

        const short* Qrow  = Q  + ((size_t)(b * SEQ) + qbase + lr) * D_MODEL + h * 64;
        const short* qprow = qp + ((size_t)bh * SEQ + qbase + lr) * 64;
        bf16x8 qf0  = *reinterpret_cast<const bf16x8*>(Qrow + lg * 8);
        bf16x8 qf1  = *reinterpret_cast<const bf16x8*>(Qrow + 32 + lg * 8);
        bf16x8 qpf0 = *reinterpret_cast<const bf16x8*>(qprow + lg * 8);
        bf16x8 qpf1 = *reinterpret_cast<const bf16x8*>(qprow + 32 + lg * 8);

        f32x4 o_acc[4] = {};
        float m_run[4], l_run[4];
        #pragma unroll
        for (int r = 0; r < 4; ++r) { m_run[r] = -1e30f; l_run[r] = 0.f; }

        int nkt = qt / 2 + 1;
        stage(0, 0);
        __syncthreads();                    // vmcnt(0) drained by compiler
        int cur = 0;

        for (int kt = 0; kt < nkt; ++kt) {
            if (kt + 1 < nkt) stage(kt + 1, cur ^ 1);

            const short* Kb  = &Ks[cur][0];
            const short* kpb = &kps[cur][0];
            const short* Vb  = &Vts[cur][0];
            f32x4 sx[4] = {}, sp[4] = {};
            __builtin_amdgcn_s_setprio(1);
            #pragma unroll
            for (int sub = 0; sub < 4; ++sub) {
                int row = sub * 16 + lr;
                bf16x8 kf0 = ldr(Kb, row, 0),  kf1 = ldr(Kb, row, 64);
                bf16x8 kq0 = ldr(kpb, row, 0), kq1 = ldr(kpb, row, 64);
                sx[sub] = __builtin_amdgcn_mfma_f32_16x16x32_bf16(qf0,  kf0, sx[sub], 0, 0, 0);
                sx[sub] = __builtin_amdgcn_mfma_f32_16x16x32_bf16(qf1,  kf1, sx[sub], 0, 0, 0);
                sp[sub] = __builtin_amdgcn_mfma_f32_16x16x32_bf16(qpf0, kq0, sp[sub], 0, 0, 0);
                sp[sub] = __builtin_amdgcn_mfma_f32_16x16x32_bf16(qpf1, kq1, sp[sub], 0, 0, 0);
            }
            __builtin_amdgcn_s_setprio(0);

            // ---- combine + mask; per-row tile max (log2 domain, scale pre-folded)
            float sc[4][4];
            float pmax[4];
            bool diag = (kt == nkt - 1);
            #pragma unroll
            for (int r = 0; r < 4; ++r) {
                int row = qbase + lg * 4 + r;
                float mx = -1e30f;
                #pragma unroll
                for (int sub = 0; sub < 4; ++sub) {
                    float v = sx[sub][r] * sp[sub][r];
                    if (diag) {
                        int col = kt * 64 + sub * 16 + lr;
                        if (col > row) v = -1e30f;
                    }
                    sc[sub][r] = v;
                    mx = fmaxf(mx, v);
                }
                pmax[r] = dpp_max16(mx);
            }

            // ---- defer-max (T13): rescale only when some row exceeds m+8
            bool need = false;
            #pragma unroll
            for (int r = 0; r < 4; ++r) need = need || (pmax[r] > m_run[r] + 8.f);
            if (__any(need)) {
                #pragma unroll
                for (int r = 0; r < 4; ++r) {
                    float m_new = fmaxf(m_run[r], pmax[r]);
                    float scale = exp2f(m_run[r] - m_new);
                    m_run[r] = m_new;
                    l_run[r] *= scale;
                    #pragma unroll
                    for (int ds = 0; ds < 4; ++ds) o_acc[ds][r] *= scale;
                }
            }
            #pragma unroll
            for (int r = 0; r < 4; ++r) {
                float s = 0.f;
                #pragma unroll
                for (int sub = 0; sub < 4; ++sub) {
                    float pv = exp2f(sc[sub][r] - m_run[r]);
                    sc[sub][r] = pv;
                    s += pv;
                }
                l_run[r] += dpp_sum16(s);
            }

            // ---- P -> bf16 -> wave-private LDS -> A-frags
            #pragma unroll
            for (int sub = 0; sub < 4; ++sub)
                #pragma unroll
                for (int r = 0; r < 4; ++r)
                    Plds[w][lg * 4 + r][sub * 16 + lr] = f2bf(sc[sub][r]);

            bf16x8 pa0 = *reinterpret_cast<bf16x8*>(&Plds[w][lr][lg * 8]);
            bf16x8 pa1 = *reinterpret_cast<bf16x8*>(&Plds[w][lr][32 + lg * 8]);

            __builtin_amdgcn_s_setprio(1);
            #pragma unroll
            for (int ds = 0; ds < 4; ++ds) {
                int row = ds * 16 + lr;
                bf16x8 vb0 = ldr(Vb, row, 0), vb1 = ldr(Vb, row, 64);
                o_acc[ds] = __builtin_amdgcn_mfma_f32_16x16x32_bf16(pa0, vb0, o_acc[ds], 0, 0, 0);
                o_acc[ds] = __builtin_amdgcn_mfma_f32_16x16x32_bf16(pa1, vb1, o_acc[ds], 0, 0, 0);
            }
            __builtin_amdgcn_s_setprio(0);

            __syncthreads();
            cur ^= 1;
        }

        #pragma unroll
        for (int ds = 0; ds < 4; ++ds)
            #pragma unroll
            for (int r = 0; r < 4; ++r) {
                int row = qbase + lg * 4 + r;
                float val = o_acc[ds][r] / l_run[r];
                ao[((size_t)(b * SEQ) + row) * D_MODEL + h * 64 + ds * 16 + lr] = f2bf(val);
            }
        __syncthreads();   // phases share LDS buffers
    }
}

// ---------------------------------------------------------------- launch
extern "C" void kernel_launch(void* const* d_in, const int* in_sizes, int n_in,
                              void* d_out, int out_size, void* d_ws, size_t ws_size,
                              hipStream_t stream) {
    const float* x     = (const float*)d_in[0];
    const float* q_pos = (const float*)d_in[1];
    const float* k_pos = (const float*)d_in[2];
    const float* Wq = (const float*)d_in[4];
    const float* bq = (const float*)d_in[5];
    const float* Wk = (const float*)d_in[6];
    const float* bk = (const float*)d_in[7];
    const float* Wv = (const float*)d_in[8];
    const float* bv = (const float*)d_in[9];
    const float* Wo = (const float*)d_in[10];
    const float* bo = (const float*)d_in[11];
    const float* ln1_g = (const float*)d_in[12];
    const float* ln1_b = (const float*)d_in[13];
    const float* ln2_g = (const float*)d_in[14];
    const float* ln2_b = (const float*)d_in[15];
    const float* W1 = (const float*)d_in[16];
    const float* b1 = (const float*)d_in[17];
    const float* W2 = (const float*)d_in[18];
    const float* b2 = (const float*)d_in[19];
    float* out = (float*)d_out;

    char* p = (char*)d_ws;
    auto alloc = [&](size_t bytes) { char* q = p; p += (bytes + 255) & ~(size_t)255; return q; };
    const size_t SA = (size_t)ROWS * D_MODEL;
    const size_t SP = (size_t)BATCH * N_HEADS * SEQ * 64;

    short* h_bf  = (short*)alloc(SA * 2);
    short* Qm    = (short*)alloc(SA * 2);
    short* Km    = (short*)alloc(SA * 2);
    short* Vm    = (short*)alloc(SA * 2);
    short* Vt    = (short*)alloc(SP * 2);
    short* ao    = (short*)alloc(SA * 2);
    short* qp_bf = (short*)alloc(SP * 2);
    short* kp_bf = (short*)alloc(SP * 2);
    short* mid   = (short*)alloc((size_t)ROWS * D_FFN * 2);
    float* x2    = (float*)alloc(SA * 4);
    float* P0    = (float*)alloc(SA * 4);
    float* P1    = (float*)alloc(SA * 4);
    short* WTq   = (short*)alloc((size_t)D_MODEL * D_MODEL * 2);
    short* WTk   = (short*)alloc((size_t)D_MODEL * D_MODEL * 2);
    short* WTv   = (short*)alloc((size_t)D_MODEL * D_MODEL * 2);
    short* WTo   = (short*)alloc((size_t)D_MODEL * D_MODEL * 2);
    short* WT1   = (short*)alloc((size_t)D_MODEL * D_FFN * 2);
    short* WT2   = (short*)alloc((size_t)D_MODEL * D_FFN * 2);

    // fused prep: 6 transposes + 2 converts + LN1 in one dispatch
    prep_kernel<<<14080, 256, 0, stream>>>(Wq, Wk, Wv, Wo, W1, W2, q_pos, k_pos,
                                           x, ln1_g, ln1_b,
                                           WTq, WTk, WTv, WTo, WT1, WT2,
                                           qp_bf, kp_bf, h_bf);

    gemm_qkv_kernel<<<dim3(D_MODEL/128, ROWS/128, 3), 256, 0, stream>>>(
        h_bf, WTq, WTk, WTv, bq, bk, bv, Qm, Km, Vm);
    transpose_v_kernel<<<dim3(SEQ/64, BATCH*N_HEADS), 256, 0, stream>>>(Vm, Vt);
    attn_mfma_kernel<<<768, 128, 0, stream>>>(Qm, Km, Vt, qp_bf, kp_bf, ao);
    gemm_wo_kernel<<<dim3(D_MODEL/128, ROWS/128, 2), 256, 0, stream>>>(ao, WTo, P0, P1);
    ln2_fuse_kernel<<<ROWS, 256, 0, stream>>>(P0, P1, bo, x, ln2_g, ln2_b, x2, h_bf);
    gemm_mfma_kernel<1, false, true><<<dim3(D_FFN/128, ROWS/128), 256, 0, stream>>>(
        h_bf, WT1, b1, nullptr, mid, ROWS, D_FFN, D_MODEL);
    gemm_w2_kernel<<<dim3(D_MODEL/128, ROWS/128, 2), 256, 0, stream>>>(mid, WT2, P0, P1);
    w2_epi_kernel<<<(int)(SA/1024), 256, 0, stream>>>(P0, P1, b2, x2, out);
}

// Round 19
// 221.976 us; speedup vs baseline: 1.0849x; 1.0364x over previous
//
#include <hip/hip_runtime.h>
#include <hip/hip_bf16.h>
#include <math.h>

#define D_MODEL 768
#define N_HEADS 12
#define D_HEAD  64
#define BATCH   2
#define SEQ     2048
#define ROWS    (BATCH*SEQ)          // 4096
#define D_FFN   (4*D_MODEL)          // 3072

typedef short bf16x8 __attribute__((ext_vector_type(8)));
typedef float f32x4  __attribute__((ext_vector_type(4)));

__device__ __forceinline__ short f2bf(float f) {
    __hip_bfloat16 h = __float2bfloat16(f);
    return *reinterpret_cast<short*>(&h);
}

// fast hardware exp2 (v_exp_f32), same accuracy class as __expf
__device__ __forceinline__ float fexp2(float x) {
    return __builtin_amdgcn_exp2f(x);
}

// 16-lane DPP reductions; VALU-only, no LDS.
template<int CTRL>
__device__ __forceinline__ float dpp_f(float x) {
    int v = __builtin_amdgcn_update_dpp(0, __float_as_int(x), CTRL, 0xF, 0xF, true);
    return __int_as_float(v);
}
__device__ __forceinline__ float dpp_max16(float x) {
    x = fmaxf(x, dpp_f<0xB1>(x));    // quad_perm xor1
    x = fmaxf(x, dpp_f<0x4E>(x));    // quad_perm xor2
    x = fmaxf(x, dpp_f<0x141>(x));   // row_half_mirror
    x = fmaxf(x, dpp_f<0x140>(x));   // row_mirror
    return x;
}
__device__ __forceinline__ float dpp_sum16(float x) {
    x += dpp_f<0xB1>(x);
    x += dpp_f<0x4E>(x);
    x += dpp_f<0x141>(x);
    x += dpp_f<0x140>(x);
    return x;
}

// Score scale folding: scores = (Q K^T)*(qp kp^T)/64, softmax via exp2.
// sqrt(log2(e))/8 folded into BOTH Q and q_pos so sx*sp is already in
// log2-domain: p = exp2(sc - m). 0.15014031^2 = log2(e)/64.
#define QSCALE 0.15014031f

// ---------------------------------------------------------------- fused prep (+LN1)
// Segments: [0,576)Wq [576,1152)Wk [1152,1728)Wv [1728,2304)Wo
//           [2304,4608)W1 [4608,6912)W2 [6912,8448)qp [8448,9984)kp
//           [9984,14080) LN1 rows
__global__ __launch_bounds__(256)
void prep_kernel(const float* __restrict__ Wq, const float* __restrict__ Wk,
                 const float* __restrict__ Wv, const float* __restrict__ Wo,
                 const float* __restrict__ W1, const float* __restrict__ W2,
                 const float* __restrict__ q_pos, const float* __restrict__ k_pos,
                 const float* __restrict__ x, const float* __restrict__ ln1_g,
                 const float* __restrict__ ln1_b,
                 short* __restrict__ WTq, short* __restrict__ WTk,
                 short* __restrict__ WTv, short* __restrict__ WTo,
                 short* __restrict__ WT1, short* __restrict__ WT2,
                 short* __restrict__ qp_bf, short* __restrict__ kp_bf,
                 short* __restrict__ h_bf) {
    int id = blockIdx.x;
    if (id >= 9984) {   // LN1 segment
        int row = id - 9984;
        const float* xr = x + (size_t)row * D_MODEL;
        int t = threadIdx.x;
        float v0 = xr[t], v1 = xr[t + 256], v2 = xr[t + 512];
        float s  = v0 + v1 + v2;
        float s2 = v0*v0 + v1*v1 + v2*v2;
        __shared__ float rs[4], rs2[4];
        #pragma unroll
        for (int off = 32; off; off >>= 1) {
            s  += __shfl_down(s, off);
            s2 += __shfl_down(s2, off);
        }
        int wv = t >> 6, ln = t & 63;
        if (ln == 0) { rs[wv] = s; rs2[wv] = s2; }
        __syncthreads();
        float S  = rs[0] + rs[1] + rs[2] + rs[3];
        float S2 = rs2[0] + rs2[1] + rs2[2] + rs2[3];
        float mu  = S * (1.0f / D_MODEL);
        float var = S2 * (1.0f / D_MODEL) - mu * mu;
        float inv = rsqrtf(var + 1e-5f);
        short* orow = h_bf + (size_t)row * D_MODEL;
        orow[t]       = f2bf((v0 - mu) * inv * ln1_g[t]       + ln1_b[t]);
        orow[t + 256] = f2bf((v1 - mu) * inv * ln1_g[t + 256] + ln1_b[t + 256]);
        orow[t + 512] = f2bf((v2 - mu) * inv * ln1_g[t + 512] + ln1_b[t + 512]);
        return;
    }
    if (id >= 6912) {   // convert segment
        int cid = id - 6912;
        bool isq = (cid < 1536);
        int c = isq ? cid : cid - 1536;          // 1536 is NOT pow2: no & trick
        const float* src = isq ? q_pos : k_pos;
        short* dst = isq ? qp_bf : kp_bf;
        float sc = isq ? QSCALE : 1.0f;
        int i = (c * 256 + threadIdx.x) * 8;
        float4 a = *reinterpret_cast<const float4*>(src + i);
        float4 b = *reinterpret_cast<const float4*>(src + i + 4);
        bf16x8 r;
        r[0]=f2bf(a.x*sc); r[1]=f2bf(a.y*sc); r[2]=f2bf(a.z*sc); r[3]=f2bf(a.w*sc);
        r[4]=f2bf(b.x*sc); r[5]=f2bf(b.y*sc); r[6]=f2bf(b.z*sc); r[7]=f2bf(b.w*sc);
        *reinterpret_cast<bf16x8*>(dst + i) = r;
        return;
    }
    const float* W; short* WT; int K, N, t;
    if (id < 576)        { W = Wq; WT = WTq; K = 768;  N = 768;  t = id; }
    else if (id < 1152)  { W = Wk; WT = WTk; K = 768;  N = 768;  t = id - 576; }
    else if (id < 1728)  { W = Wv; WT = WTv; K = 768;  N = 768;  t = id - 1152; }
    else if (id < 2304)  { W = Wo; WT = WTo; K = 768;  N = 768;  t = id - 1728; }
    else if (id < 4608)  { W = W1; WT = WT1; K = 768;  N = 3072; t = id - 2304; }
    else                 { W = W2; WT = WT2; K = 3072; N = 768;  t = id - 4608; }
    int nb = N >> 5;
    int n0 = (t % nb) * 32, k0 = (t / nb) * 32;
    __shared__ float tile[32][33];
    int tx = threadIdx.x & 31, ty = threadIdx.x >> 5;   // 32 x 8
    #pragma unroll
    for (int i = 0; i < 4; ++i)
        tile[ty + 8*i][tx] = W[(size_t)(k0 + ty + 8*i) * N + n0 + tx];
    __syncthreads();
    #pragma unroll
    for (int i = 0; i < 4; ++i)
        WT[(size_t)(n0 + ty + 8*i) * K + k0 + tx] = f2bf(tile[tx][ty + 8*i]);
}

// Vm [ROWS][768] bf16 -> Vt [24][64][2048] bf16 (per-head V^T)
__global__ __launch_bounds__(256)
void transpose_v_kernel(const short* __restrict__ Vm, short* __restrict__ Vt) {
    __shared__ short tile[64][72];
    int kt = blockIdx.x;        // 32 k-tiles of 64
    int bh = blockIdx.y;        // 24
    int b = bh / N_HEADS, h = bh % N_HEADS;
    int tid = threadIdx.x;
    int row = tid >> 2, c16 = (tid & 3) * 16;
    const short* src = Vm + ((size_t)(b * SEQ) + kt * 64 + row) * D_MODEL + h * 64 + c16;
    *reinterpret_cast<bf16x8*>(&tile[row][c16])     = *reinterpret_cast<const bf16x8*>(src);
    *reinterpret_cast<bf16x8*>(&tile[row][c16 + 8]) = *reinterpret_cast<const bf16x8*>(src + 8);
    __syncthreads();
    int d = tid >> 2, k16 = (tid & 3) * 16;
    short o[16];
    #pragma unroll
    for (int j = 0; j < 16; ++j) o[j] = tile[k16 + j][d];
    short* dst = Vt + ((size_t)bh * 64 + d) * SEQ + kt * 64 + k16;
    *reinterpret_cast<bf16x8*>(dst)     = *reinterpret_cast<bf16x8*>(&o[0]);
    *reinterpret_cast<bf16x8*>(dst + 8) = *reinterpret_cast<bf16x8*>(&o[8]);
}

// ---------------------------------------------------------------- LN2 fused with Wo epilogue
// x2 = P0 + P1 + bo + x ; h_bf = LN(x2)
__global__ __launch_bounds__(256)
void ln2_fuse_kernel(const float* __restrict__ P0, const float* __restrict__ P1,
                     const float* __restrict__ bo, const float* __restrict__ x,
                     const float* __restrict__ g, const float* __restrict__ beta,
                     float* __restrict__ x2, short* __restrict__ out) {
    int row = blockIdx.x;
    size_t base = (size_t)row * D_MODEL;
    int t = threadIdx.x;
    float v0 = P0[base + t]       + P1[base + t]       + bo[t]       + x[base + t];
    float v1 = P0[base + t + 256] + P1[base + t + 256] + bo[t + 256] + x[base + t + 256];
    float v2 = P0[base + t + 512] + P1[base + t + 512] + bo[t + 512] + x[base + t + 512];
    x2[base + t] = v0; x2[base + t + 256] = v1; x2[base + t + 512] = v2;
    float s  = v0 + v1 + v2;
    float s2 = v0*v0 + v1*v1 + v2*v2;
    __shared__ float rs[4], rs2[4];
    #pragma unroll
    for (int off = 32; off; off >>= 1) {
        s  += __shfl_down(s, off);
        s2 += __shfl_down(s2, off);
    }
    int wv = t >> 6, ln = t & 63;
    if (ln == 0) { rs[wv] = s; rs2[wv] = s2; }
    __syncthreads();
    float S  = rs[0] + rs[1] + rs[2] + rs[3];
    float S2 = rs2[0] + rs2[1] + rs2[2] + rs2[3];
    float mu  = S * (1.0f / D_MODEL);
    float var = S2 * (1.0f / D_MODEL) - mu * mu;
    float inv = rsqrtf(var + 1e-5f);
    short* orow = out + base;
    orow[t]       = f2bf((v0 - mu) * inv * g[t]       + beta[t]);
    orow[t + 256] = f2bf((v1 - mu) * inv * g[t + 256] + beta[t + 256]);
    orow[t + 512] = f2bf((v2 - mu) * inv * g[t + 512] + beta[t + 512]);
}

// ---------------------------------------------------------------- bf16 MFMA GEMM
// Double-buffered LDS staging. ACT: 0 = bias[+res], 1 = bias+GELU, 2 = raw partial.
template<int ACT, bool RES, bool OUTBF>
__device__ __forceinline__
void gemm_body(const short* __restrict__ A, const short* __restrict__ WT,
               const float* __restrict__ bias, const float* __restrict__ res,
               void* __restrict__ Cout, int M, int N, int Kloop, int Kstride,
               float oscale) {
    __shared__ short As[2][128 * 32];
    __shared__ short Bs[2][128 * 32];
    const int tid = threadIdx.x;
    const int w = tid >> 6, lane = tid & 63;
    const int lr = lane & 15, lg = lane >> 4;
    const int wm = w >> 1, wn = w & 1;
    const int bm = blockIdx.y * 128, bn = blockIdx.x * 128;

    f32x4 acc[4][4] = {};

    const int srow = w * 32 + (lane >> 2);
    const int scol = (lane & 3) * 8;
    const short* Ag = A  + (size_t)(bm + srow) * Kstride + scol;
    const short* Bg = WT + (size_t)(bn + srow) * Kstride + scol;

    auto stage = [&](int k0, int buf) {
        #pragma unroll
        for (int r = 0; r < 2; ++r) {
            __builtin_amdgcn_global_load_lds(
                (const __attribute__((address_space(1))) void*)(Ag + (size_t)r * 16 * Kstride + k0),
                (__attribute__((address_space(3))) void*)(&As[buf][0] + w * 1024 + r * 512),
                16, 0, 0);
            __builtin_amdgcn_global_load_lds(
                (const __attribute__((address_space(1))) void*)(Bg + (size_t)r * 16 * Kstride + k0),
                (__attribute__((address_space(3))) void*)(&Bs[buf][0] + w * 1024 + r * 512),
                16, 0, 0);
        }
    };

    stage(0, 0);
    __syncthreads();
    int cur = 0;

    for (int k0 = 0; k0 < Kloop; k0 += 32) {
        if (k0 + 32 < Kloop) stage(k0 + 32, cur ^ 1);

        bf16x8 af[4], bfr[4];
        #pragma unroll
        for (int mi = 0; mi < 4; ++mi)
            af[mi] = *reinterpret_cast<const bf16x8*>(&As[cur][0] + (wm*64 + mi*16 + lr) * 32 + lg*8);
        #pragma unroll
        for (int nj = 0; nj < 4; ++nj)
            bfr[nj] = *reinterpret_cast<const bf16x8*>(&Bs[cur][0] + (wn*64 + nj*16 + lr) * 32 + lg*8);
        __builtin_amdgcn_s_setprio(1);
        #pragma unroll
        for (int mi = 0; mi < 4; ++mi)
            #pragma unroll
            for (int nj = 0; nj < 4; ++nj)
                acc[mi][nj] = __builtin_amdgcn_mfma_f32_16x16x32_bf16(af[mi], bfr[nj], acc[mi][nj], 0, 0, 0);
        __builtin_amdgcn_s_setprio(0);

        __syncthreads();
        cur ^= 1;
    }

    float bias_v[4] = {0.f, 0.f, 0.f, 0.f};
    if constexpr (ACT != 2) {
        #pragma unroll
        for (int nj = 0; nj < 4; ++nj) bias_v[nj] = bias[bn + wn*64 + nj*16 + lr];
    }

    #pragma unroll
    for (int mi = 0; mi < 4; ++mi) {
        #pragma unroll
        for (int j = 0; j < 4; ++j) {
            size_t m = bm + wm*64 + mi*16 + lg*4 + j;
            #pragma unroll
            for (int nj = 0; nj < 4; ++nj) {
                size_t n = bn + wn*64 + nj*16 + lr;
                float v = acc[mi][nj][j] + bias_v[nj];
                if (RES) v += res[m * N + n];
                if (ACT == 1) v = 0.5f * v * (1.0f + erff(v * 0.70710678118f));
                if (OUTBF) ((short*)Cout)[m * N + n] = f2bf(v * oscale);
                else       ((float*)Cout)[m * N + n] = v;
            }
        }
    }
}

template<int ACT, bool RES, bool OUTBF>
__global__ __launch_bounds__(256)
void gemm_mfma_kernel(const short* __restrict__ A, const short* __restrict__ WT,
                      const float* __restrict__ bias, const float* __restrict__ res,
                      void* __restrict__ Cout, int M, int N, int K) {
    gemm_body<ACT, RES, OUTBF>(A, WT, bias, res, Cout, M, N, K, K, 1.0f);
}

__global__ __launch_bounds__(256)
void gemm_qkv_kernel(const short* __restrict__ A,
                     const short* __restrict__ WTq, const short* __restrict__ WTk,
                     const short* __restrict__ WTv,
                     const float* __restrict__ bq, const float* __restrict__ bk,
                     const float* __restrict__ bv,
                     short* __restrict__ Qm, short* __restrict__ Km, short* __restrict__ Vm) {
    const short* WT; const float* bias; short* C; float sc;
    if (blockIdx.z == 0)      { WT = WTq; bias = bq; C = Qm; sc = QSCALE; }  // fold scale
    else if (blockIdx.z == 1) { WT = WTk; bias = bk; C = Km; sc = 1.0f; }
    else                      { WT = WTv; bias = bv; C = Vm; sc = 1.0f; }
    gemm_body<0, false, true>(A, WT, bias, nullptr, C, ROWS, D_MODEL, D_MODEL, D_MODEL, sc);
}

// Wo K-split: z in {0,1}, each half K=384, raw fp32 partials (384 blocks)
__global__ __launch_bounds__(256)
void gemm_wo_kernel(const short* __restrict__ ao, const short* __restrict__ WTo,
                    float* __restrict__ P0, float* __restrict__ P1) {
    int z = blockIdx.z;
    gemm_body<2, false, false>(ao + z * 384, WTo + z * 384, nullptr, nullptr,
                               z ? P1 : P0, ROWS, D_MODEL, 384, D_MODEL, 1.0f);
}

// W2 K-split: z in {0,1}, each half K=1536, raw fp32 partials (384 blocks)
__global__ __launch_bounds__(256)
void gemm_w2_kernel(const short* __restrict__ mid, const short* __restrict__ WT2,
                    float* __restrict__ P0, float* __restrict__ P1) {
    int z = blockIdx.z;
    gemm_body<2, false, false>(mid + z * 1536, WT2 + z * 1536, nullptr, nullptr,
                               z ? P1 : P0, ROWS, D_MODEL, 1536, D_FFN, 1.0f);
}

// out = P0 + P1 + b2 + x2
__global__ __launch_bounds__(256)
void w2_epi_kernel(const float* __restrict__ P0, const float* __restrict__ P1,
                   const float* __restrict__ b2, const float* __restrict__ x2,
                   float* __restrict__ out) {
    size_t i = ((size_t)blockIdx.x * 256 + threadIdx.x) * 4;
    int n = (int)(i % D_MODEL);
    float4 p0 = *reinterpret_cast<const float4*>(P0 + i);
    float4 p1 = *reinterpret_cast<const float4*>(P1 + i);
    float4 xr = *reinterpret_cast<const float4*>(x2 + i);
    float4 bb = *reinterpret_cast<const float4*>(b2 + n);
    float4 o;
    o.x = p0.x + p1.x + xr.x + bb.x;
    o.y = p0.y + p1.y + xr.y + bb.y;
    o.z = p0.z + p1.z + xr.z + bb.z;
    o.w = p0.w + p1.w + xr.w + bb.w;
    *reinterpret_cast<float4*>(out + i) = o;
}

// ---------------------------------------------------------------- MFMA flash attention v17
// r16 structure (all operands LDS-staged, double-buffered, 53760 B ->
// 3 blocks/CU) + log2-domain softmax via HW v_exp_f32 (__builtin_amdgcn_exp2f).
__global__ __launch_bounds__(128)
void attn_mfma_kernel(const short* __restrict__ Q, const short* __restrict__ K,
                      const short* __restrict__ Vt, const short* __restrict__ qp,
                      const short* __restrict__ kp, short* __restrict__ ao) {
    __shared__ short Ks[2][4096];       // 64 keys x 64 d, swizzled
    __shared__ short kps[2][4096];
    __shared__ short Vts[2][4096];      // 64 d x 64 keys, swizzled
    __shared__ short Plds[2][16][72];   // per-wave P tile (53760 B total)

    int lin = blockIdx.x;               // 0..767
    int wid = (lin & 7) * 96 + (lin >> 3);  // bijective XCD swizzle (768=8*96)
    int bh = wid >> 5;                  // 3 heads per XCD
    int pair = wid & 31;                // uniform-work pair index
    int b = bh / N_HEADS, h = bh % N_HEADS;
    int tid = threadIdx.x, w = tid >> 6, lane = tid & 63;
    int lr = lane & 15, lg = lane >> 4;

    const short* Kh  = K  + (size_t)(b * SEQ) * D_MODEL + h * 64;
    const short* kph = kp + (size_t)bh * SEQ * 64;
    const short* Vth = Vt + (size_t)bh * 64 * SEQ;

    const int s_sub  = lane >> 3;                      // row within 8-group
    const int s_colb = ((lane & 7) ^ s_sub) << 4;      // swizzled col byte

    auto stage = [&](int kt, int buf) {
        #pragma unroll
        for (int j = 0; j < 4; ++j) {
            int row = (w * 4 + j) * 8 + s_sub;
            int ldsoff = (w * 4 + j) * 1024;
            __builtin_amdgcn_global_load_lds(
                (const __attribute__((address_space(1))) void*)
                    ((const char*)(Kh + (size_t)(kt * 64 + row) * D_MODEL) + s_colb),
                (__attribute__((address_space(3))) void*)((char*)&Ks[buf][0] + ldsoff), 16, 0, 0);
            __builtin_amdgcn_global_load_lds(
                (const __attribute__((address_space(1))) void*)
                    ((const char*)(kph + (size_t)(kt * 64 + row) * 64) + s_colb),
                (__attribute__((address_space(3))) void*)((char*)&kps[buf][0] + ldsoff), 16, 0, 0);
            __builtin_amdgcn_global_load_lds(
                (const __attribute__((address_space(1))) void*)
                    ((const char*)(Vth + (size_t)row * SEQ + kt * 64) + s_colb),
                (__attribute__((address_space(3))) void*)((char*)&Vts[buf][0] + ldsoff), 16, 0, 0);
        }
    };
    auto ldr = [&](const short* base, int row, int halfb) -> bf16x8 {
        int off = row * 128 + ((halfb + lg * 16) ^ ((row & 7) << 4));
        return *reinterpret_cast<const bf16x8*>((const char*)base + off);
    };

    #pragma unroll
    for (int ph = 0; ph < 2; ++ph) {
        int qt = ph ? 63 - pair : pair;     // 32-row q-tile index, 0..63
        int qbase = qt * 32 + w * 16;

        const short* Qrow  = Q  + ((size_t)(b * SEQ) + qbase + lr) * D_MODEL + h * 64;
        const short* qprow = qp + ((size_t)bh * SEQ + qbase + lr) * 64;
        bf16x8 qf0  = *reinterpret_cast<const bf16x8*>(Qrow + lg * 8);
        bf16x8 qf1  = *reinterpret_cast<const bf16x8*>(Qrow + 32 + lg * 8);
        bf16x8 qpf0 = *reinterpret_cast<const bf16x8*>(qprow + lg * 8);
        bf16x8 qpf1 = *reinterpret_cast<const bf16x8*>(qprow + 32 + lg * 8);

        f32x4 o_acc[4] = {};
        float m_run[4], l_run[4];
        #pragma unroll
        for (int r = 0; r < 4; ++r) { m_run[r] = -1e30f; l_run[r] = 0.f; }

        int nkt = qt / 2 + 1;
        stage(0, 0);
        __syncthreads();                    // vmcnt(0) drained by compiler
        int cur = 0;

        for (int kt = 0; kt < nkt; ++kt) {
            if (kt + 1 < nkt) stage(kt + 1, cur ^ 1);

            const short* Kb  = &Ks[cur][0];
            const short* kpb = &kps[cur][0];
            const short* Vb  = &Vts[cur][0];
            f32x4 sx[4] = {}, sp[4] = {};
            __builtin_amdgcn_s_setprio(1);
            #pragma unroll
            for (int sub = 0; sub < 4; ++sub) {
                int row = sub * 16 + lr;
                bf16x8 kf0 = ldr(Kb, row, 0),  kf1 = ldr(Kb, row, 64);
                bf16x8 kq0 = ldr(kpb, row, 0), kq1 = ldr(kpb, row, 64);
                sx[sub] = __builtin_amdgcn_mfma_f32_16x16x32_bf16(qf0,  kf0, sx[sub], 0, 0, 0);
                sx[sub] = __builtin_amdgcn_mfma_f32_16x16x32_bf16(qf1,  kf1, sx[sub], 0, 0, 0);
                sp[sub] = __builtin_amdgcn_mfma_f32_16x16x32_bf16(qpf0, kq0, sp[sub], 0, 0, 0);
                sp[sub] = __builtin_amdgcn_mfma_f32_16x16x32_bf16(qpf1, kq1, sp[sub], 0, 0, 0);
            }
            __builtin_amdgcn_s_setprio(0);

            // ---- combine + mask; per-row tile max (log2 domain, scale pre-folded)
            float sc[4][4];
            float pmax[4];
            bool diag = (kt == nkt - 1);
            #pragma unroll
            for (int r = 0; r < 4; ++r) {
                int row = qbase + lg * 4 + r;
                float mx = -1e30f;
                #pragma unroll
                for (int sub = 0; sub < 4; ++sub) {
                    float v = sx[sub][r] * sp[sub][r];
                    if (diag) {
                        int col = kt * 64 + sub * 16 + lr;
                        if (col > row) v = -1e30f;
                    }
                    sc[sub][r] = v;
                    mx = fmaxf(mx, v);
                }
                pmax[r] = dpp_max16(mx);
            }

            // ---- defer-max (T13): rescale only when some row exceeds m+8
            bool need = false;
            #pragma unroll
            for (int r = 0; r < 4; ++r) need = need || (pmax[r] > m_run[r] + 8.f);
            if (__any(need)) {
                #pragma unroll
                for (int r = 0; r < 4; ++r) {
                    float m_new = fmaxf(m_run[r], pmax[r]);
                    float scale = fexp2(m_run[r] - m_new);
                    m_run[r] = m_new;
                    l_run[r] *= scale;
                    #pragma unroll
                    for (int ds = 0; ds < 4; ++ds) o_acc[ds][r] *= scale;
                }
            }
            #pragma unroll
            for (int r = 0; r < 4; ++r) {
                float s = 0.f;
                #pragma unroll
                for (int sub = 0; sub < 4; ++sub) {
                    float pv = fexp2(sc[sub][r] - m_run[r]);
                    sc[sub][r] = pv;
                    s += pv;
                }
                l_run[r] += dpp_sum16(s);
            }

            // ---- P -> bf16 -> wave-private LDS -> A-frags
            #pragma unroll
            for (int sub = 0; sub < 4; ++sub)
                #pragma unroll
                for (int r = 0; r < 4; ++r)
                    Plds[w][lg * 4 + r][sub * 16 + lr] = f2bf(sc[sub][r]);

            bf16x8 pa0 = *reinterpret_cast<bf16x8*>(&Plds[w][lr][lg * 8]);
            bf16x8 pa1 = *reinterpret_cast<bf16x8*>(&Plds[w][lr][32 + lg * 8]);

            __builtin_amdgcn_s_setprio(1);
            #pragma unroll
            for (int ds = 0; ds < 4; ++ds) {
                int row = ds * 16 + lr;
                bf16x8 vb0 = ldr(Vb, row, 0), vb1 = ldr(Vb, row, 64);
                o_acc[ds] = __builtin_amdgcn_mfma_f32_16x16x32_bf16(pa0, vb0, o_acc[ds], 0, 0, 0);
                o_acc[ds] = __builtin_amdgcn_mfma_f32_16x16x32_bf16(pa1, vb1, o_acc[ds], 0, 0, 0);
            }
            __builtin_amdgcn_s_setprio(0);

            __syncthreads();
            cur ^= 1;
        }

        #pragma unroll
        for (int ds = 0; ds < 4; ++ds)
            #pragma unroll
            for (int r = 0; r < 4; ++r) {
                int row = qbase + lg * 4 + r;
                float val = o_acc[ds][r] / l_run[r];
                ao[((size_t)(b * SEQ) + row) * D_MODEL + h * 64 + ds * 16 + lr] = f2bf(val);
            }
        __syncthreads();   // phases share LDS buffers
    }
}

// ---------------------------------------------------------------- launch
extern "C" void kernel_launch(void* const* d_in, const int* in_sizes, int n_in,
                              void* d_out, int out_size, void* d_ws, size_t ws_size,
                              hipStream_t stream) {
    const float* x     = (const float*)d_in[0];
    const float* q_pos = (const float*)d_in[1];
    const float* k_pos = (const float*)d_in[2];
    const float* Wq = (const float*)d_in[4];
    const float* bq = (const float*)d_in[5];
    const float* Wk = (const float*)d_in[6];
    const float* bk = (const float*)d_in[7];
    const float* Wv = (const float*)d_in[8];
    const float* bv = (const float*)d_in[9];
    const float* Wo = (const float*)d_in[10];
    const float* bo = (const float*)d_in[11];
    const float* ln1_g = (const float*)d_in[12];
    const float* ln1_b = (const float*)d_in[13];
    const float* ln2_g = (const float*)d_in[14];
    const float* ln2_b = (const float*)d_in[15];
    const float* W1 = (const float*)d_in[16];
    const float* b1 = (const float*)d_in[17];
    const float* W2 = (const float*)d_in[18];
    const float* b2 = (const float*)d_in[19];
    float* out = (float*)d_out;

    char* p = (char*)d_ws;
    auto alloc = [&](size_t bytes) { char* q = p; p += (bytes + 255) & ~(size_t)255; return q; };
    const size_t SA = (size_t)ROWS * D_MODEL;
    const size_t SP = (size_t)BATCH * N_HEADS * SEQ * 64;

    short* h_bf  = (short*)alloc(SA * 2);
    short* Qm    = (short*)alloc(SA * 2);
    short* Km    = (short*)alloc(SA * 2);
    short* Vm    = (short*)alloc(SA * 2);
    short* Vt    = (short*)alloc(SP * 2);
    short* ao    = (short*)alloc(SA * 2);
    short* qp_bf = (short*)alloc(SP * 2);
    short* kp_bf = (short*)alloc(SP * 2);
    short* mid   = (short*)alloc((size_t)ROWS * D_FFN * 2);
    float* x2    = (float*)alloc(SA * 4);
    float* P0    = (float*)alloc(SA * 4);
    float* P1    = (float*)alloc(SA * 4);
    short* WTq   = (short*)alloc((size_t)D_MODEL * D_MODEL * 2);
    short* WTk   = (short*)alloc((size_t)D_MODEL * D_MODEL * 2);
    short* WTv   = (short*)alloc((size_t)D_MODEL * D_MODEL * 2);
    short* WTo   = (short*)alloc((size_t)D_MODEL * D_MODEL * 2);
    short* WT1   = (short*)alloc((size_t)D_MODEL * D_FFN * 2);
    short* WT2   = (short*)alloc((size_t)D_MODEL * D_FFN * 2);

    // fused prep: 6 transposes + 2 converts + LN1 in one dispatch
    prep_kernel<<<14080, 256, 0, stream>>>(Wq, Wk, Wv, Wo, W1, W2, q_pos, k_pos,
                                           x, ln1_g, ln1_b,
                                           WTq, WTk, WTv, WTo, WT1, WT2,
                                           qp_bf, kp_bf, h_bf);

    gemm_qkv_kernel<<<dim3(D_MODEL/128, ROWS/128, 3), 256, 0, stream>>>(
        h_bf, WTq, WTk, WTv, bq, bk, bv, Qm, Km, Vm);
    transpose_v_kernel<<<dim3(SEQ/64, BATCH*N_HEADS), 256, 0, stream>>>(Vm, Vt);
    attn_mfma_kernel<<<768, 128, 0, stream>>>(Qm, Km, Vt, qp_bf, kp_bf, ao);
    gemm_wo_kernel<<<dim3(D_MODEL/128, ROWS/128, 2), 256, 0, stream>>>(ao, WTo, P0, P1);
    ln2_fuse_kernel<<<ROWS, 256, 0, stream>>>(P0, P1, bo, x, ln2_g, ln2_b, x2, h_bf);
    gemm_mfma_kernel<1, false, true><<<dim3(D_FFN/128, ROWS/128), 256, 0, stream>>>(
        h_bf, WT1, b1, nullptr, mid, ROWS, D_FFN, D_MODEL);
    gemm_w2_kernel<<<dim3(D_MODEL/128, ROWS/128, 2), 256, 0, stream>>>(mid, WT2, P0, P1);
    w2_epi_kernel<<<(int)(SA/1024), 256, 0, stream>>>(P0, P1, b2, x2, out);
}